// Round 4
// baseline (818.354 us; speedup 1.0000x reference)
//
#include <hip/hip_runtime.h>

#define B_  16
#define T_  512
#define M_  2048
#define C_  512
#define NEGV (-1e30f)
#define L2E 1.4426950408889634f
#define LN2 0.69314718055994531f

typedef unsigned short u16;
typedef unsigned int   u32;
using bf16x8 = __attribute__((ext_vector_type(8))) short;
using f32x4  = __attribute__((ext_vector_type(4))) float;

__device__ __forceinline__ u16 f2bf(float x) {
  u32 u = __float_as_uint(x);
  return (u16)((u + 0x7FFFu + ((u >> 16) & 1u)) >> 16);
}
__device__ __forceinline__ float bf2f(u16 u) {
  return __uint_as_float(((u32)u) << 16);
}

// 64-lane inclusive add-scan via DPP (row_shr 1/2/4/8, bcast15, bcast31)
__device__ __forceinline__ float wscan_add(float x) {
  x += __int_as_float(__builtin_amdgcn_update_dpp(0, __float_as_int(x), 0x111, 0xF, 0xF, true));
  x += __int_as_float(__builtin_amdgcn_update_dpp(0, __float_as_int(x), 0x112, 0xF, 0xF, true));
  x += __int_as_float(__builtin_amdgcn_update_dpp(0, __float_as_int(x), 0x114, 0xF, 0xF, true));
  x += __int_as_float(__builtin_amdgcn_update_dpp(0, __float_as_int(x), 0x118, 0xF, 0xF, true));
  x += __int_as_float(__builtin_amdgcn_update_dpp(0, __float_as_int(x), 0x142, 0xA, 0xF, true));
  x += __int_as_float(__builtin_amdgcn_update_dpp(0, __float_as_int(x), 0x143, 0xC, 0xF, true));
  return x;
}

// ---------------------------------------------------------------------------
// K1: energy GEMM (bf16 MFMA) + gumbel + /temperature -> log_e [B,T,M]
// ---------------------------------------------------------------------------
__launch_bounds__(256)
__global__ void k1_energy(const float* __restrict__ text, const float* __restrict__ mel,
                          const float* __restrict__ noise, const float* __restrict__ ratio,
                          float* __restrict__ log_e)
{
  __shared__ __align__(16) short As[128][40];
  __shared__ __align__(16) short Bs[128][40];
  const int b   = blockIdx.z;
  const int t0  = blockIdx.x * 128;
  const int m0  = blockIdx.y * 128;
  const int tid = threadIdx.x;
  const int lane = tid & 63, wid = tid >> 6;
  const int wr = wid >> 1, wc = wid & 1;
  const float* Ab = text + (size_t)b * T_ * C_;
  const float* Bb = mel  + (size_t)b * M_ * C_;
  f32x4 acc[4][4];
#pragma unroll
  for (int i = 0; i < 4; ++i)
#pragma unroll
    for (int j = 0; j < 4; ++j) acc[i][j] = (f32x4){0.f, 0.f, 0.f, 0.f};

  const int kq = (tid & 7) * 4;
  const int rb = tid >> 3;
  for (int kk = 0; kk < C_; kk += 32) {
    __syncthreads();
#pragma unroll
    for (int it = 0; it < 4; ++it) {
      int r = rb + it * 32;
      float4 va = *(const float4*)(Ab + (size_t)(t0 + r) * C_ + kk + kq);
      As[r][kq + 0] = (short)f2bf(va.x); As[r][kq + 1] = (short)f2bf(va.y);
      As[r][kq + 2] = (short)f2bf(va.z); As[r][kq + 3] = (short)f2bf(va.w);
      float4 vb = *(const float4*)(Bb + (size_t)(m0 + r) * C_ + kk + kq);
      Bs[r][kq + 0] = (short)f2bf(vb.x); Bs[r][kq + 1] = (short)f2bf(vb.y);
      Bs[r][kq + 2] = (short)f2bf(vb.z); Bs[r][kq + 3] = (short)f2bf(vb.w);
    }
    __syncthreads();
    const int k0 = (lane >> 4) * 8;
    bf16x8 af[4], bfr[4];
#pragma unroll
    for (int i = 0; i < 4; ++i) {
      af[i]  = *(const bf16x8*)&As[wr * 64 + i * 16 + (lane & 15)][k0];
      bfr[i] = *(const bf16x8*)&Bs[wc * 64 + i * 16 + (lane & 15)][k0];
    }
#pragma unroll
    for (int i = 0; i < 4; ++i)
#pragma unroll
      for (int j = 0; j < 4; ++j)
        acc[i][j] = __builtin_amdgcn_mfma_f32_16x16x32_bf16(af[i], bfr[j], acc[i][j], 0, 0, 0);
  }
  const float invT = 1.0f / (0.1f + 0.9f * ratio[0]);
#pragma unroll
  for (int i = 0; i < 4; ++i) {
#pragma unroll
    for (int j = 0; j < 4; ++j) {
#pragma unroll
      for (int rr = 0; rr < 4; ++rr) {
        int t = t0 + wr * 64 + i * 16 + (lane >> 4) * 4 + rr;
        int m = m0 + wc * 64 + j * 16 + (lane & 15);
        size_t idx = ((size_t)b * T_ + t) * M_ + m;
        float en = acc[i][j][rr] * (1.0f / 512.0f);
        float u  = noise[idx];
        float nl = -LN2 * __builtin_amdgcn_logf(u);    // -ln u  (>0)
        float g  = -LN2 * __builtin_amdgcn_logf(nl);   // -ln(-ln u)
        log_e[idx] = (en + g) * invT;
      }
    }
  }
}

// ---------------------------------------------------------------------------
// K3a: per-chunk partial sums of text over t (chunk = 64 rows)
// ---------------------------------------------------------------------------
__launch_bounds__(512)
__global__ void k3a_partial(const float* __restrict__ text, float* __restrict__ partial)
{
  const int b = blockIdx.x >> 3, ch = blockIdx.x & 7, c = threadIdx.x;
  const float* tb = text + (size_t)b * T_ * C_ + (size_t)ch * 64 * C_ + c;
  float s = 0.f;
#pragma unroll 8
  for (int tt = 0; tt < 64; ++tt) s += tb[(size_t)tt * C_];
  partial[((size_t)b * 8 + ch) * C_ + c] = s;
}

// ---------------------------------------------------------------------------
// K3b: suffix[b,t,c] = sum_{t'>=t} text[b,t',c]; layout [B][T+1][C], row T = 0
// ---------------------------------------------------------------------------
__launch_bounds__(512)
__global__ void k3b_suffix(const float* __restrict__ text, const float* __restrict__ partial,
                           float* __restrict__ suffix)
{
  const int b = blockIdx.x >> 3, ch = blockIdx.x & 7, c = threadIdx.x;
  float off = 0.f;
  for (int ch2 = ch + 1; ch2 < 8; ++ch2) off += partial[((size_t)b * 8 + ch2) * C_ + c];
  const float* tb = text + (size_t)b * T_ * C_ + (size_t)ch * 64 * C_ + c;
  float* sb = suffix + (size_t)b * (T_ + 1) * C_ + (size_t)ch * 64 * C_ + c;
  if (ch == 7) sb[(size_t)64 * C_] = 0.f;   // row T_
  float s = off;
  for (int tt = 63; tt >= 0; --tt) {
    s += tb[(size_t)tt * C_];
    sb[(size_t)tt * C_] = s;
  }
}

// ---------------------------------------------------------------------------
// K3t: textT[b,c,t] = bf16(text[b,t,c])  (LDS transpose tiles)
// ---------------------------------------------------------------------------
__launch_bounds__(256)
__global__ void k3t_textT(const float* __restrict__ text, u16* __restrict__ textT)
{
  __shared__ u16 tile[64][66];
  const int b  = blockIdx.z;
  const int t0 = blockIdx.x * 64;
  const int c0 = blockIdx.y * 64;
  const int tid = threadIdx.x;
  const int j = tid & 63, i4 = tid >> 6;
#pragma unroll
  for (int it = 0; it < 16; ++it) {
    int i = it * 4 + i4;
    tile[i][j] = f2bf(text[((size_t)b * T_ + t0 + i) * C_ + c0 + j]);
  }
  __syncthreads();
#pragma unroll
  for (int it = 0; it < 16; ++it) {
    int cc = it * 4 + i4;
    textT[((size_t)b * C_ + c0 + cc) * T_ + t0 + j] = tile[j][cc];
  }
}

// ---------------------------------------------------------------------------
// K4: alpha (blocks 0..15) / beta (blocks 16..31) DP. ONE WAVE per chain.
//     64 threads, 32 cols/lane, no LDS/barriers. log_S computed IN-REGISTER
//     per row (k2 eliminated): t=exp2(le*L2E-D2), cumsum -> S_row.
//     Alpha divides by S_row (v_rcp); beta uses log2(S_row).
//     Single 8-load prefetch per step, pinned with sched_barrier.
// ---------------------------------------------------------------------------
__launch_bounds__(64, 1)
__global__ void k4_dp(const float* __restrict__ log_e, const float* __restrict__ ratio,
                      float* __restrict__ alpha_out, float* __restrict__ beta_out)
{
  const int blk = blockIdx.x;
  const int b   = blk & 15;
  const int lane = threadIdx.x & 63;
  const int c0 = lane * 32;
  const float invT = 1.0f / (0.1f + 0.9f * ratio[0]);
  const float MLn = 14.5f * invT;          // bound on max(log_e)
  const float D2  = MLn * L2E;             // S_row reference (log2)
  const float TWO_D2 = 2.0f * D2;
  const float KB  = 18.4413f * invT;
  const float KB2 = KB * L2E;
  const float* LE = log_e + (size_t)b * T_ * M_;

  float le[2][32], ww[32], tt[32], ev[32];
  float Cv, dC2p;

  if (blk < 16) {
    // ======================= alpha =======================
    float* AO = alpha_out + (size_t)b * T_ * M_;

#define ALD(BUF, R) { const float* p_ = LE + (size_t)(R) * M_ + c0; \
    _Pragma("unroll") for (int g = 0; g < 8; ++g) { \
      float4 v_ = *(const float4*)(p_ + 4*g); \
      le[BUF][4*g+0]=v_.x; le[BUF][4*g+1]=v_.y; le[BUF][4*g+2]=v_.z; le[BUF][4*g+3]=v_.w; } }

    ALD(0, 0) ALD(1, 1)
    Cv   = 1.0f;
    dC2p = -(1.0f * L2E) - D2;
#pragma unroll
    for (int e = 0; e < 32; ++e) ww[e] = NEGV;

#define ASTEP(BUF, RR) { \
    const int r_ = (RR); \
    _Pragma("unroll") for (int e = 0; e < 32; ++e) \
      tt[e] = __builtin_amdgcn_exp2f(__builtin_fmaf(le[BUF][e], L2E, -D2)); \
    _Pragma("unroll") for (int c = 0; c < 4; ++c) \
      _Pragma("unroll") for (int k = 6; k >= 0; --k) tt[8*c+k] += tt[8*c+k+1]; \
    { float lt = (tt[0] + tt[8]) + (tt[16] + tt[24]); \
      float incl = wscan_add(lt); \
      float Tot = __shfl(incl, 63); \
      float crs = fmaxf(Tot - incl, 0.f); \
      float s3 = crs, s2 = tt[24]+crs, s1 = tt[16]+s2, s0 = tt[8]+s1; \
      _Pragma("unroll") for (int k = 0; k < 8; ++k) { \
        tt[k] += s0; tt[8+k] += s1; tt[16+k] += s2; tt[24+k] += s3; } } \
    { float w31s = __shfl_up(ww[31], 1); \
      float wm1 = (lane == 0) ? ((r_ == 0) ? 0.f : NEGV) : w31s; \
      ev[0] = __builtin_amdgcn_exp2f(wm1 + dC2p) * __builtin_amdgcn_rcpf(tt[0]); \
      _Pragma("unroll") for (int e = 1; e < 32; ++e) \
        ev[e] = __builtin_amdgcn_exp2f(ww[e-1] + dC2p) * __builtin_amdgcn_rcpf(tt[e]); } \
    _Pragma("unroll") for (int c = 0; c < 4; ++c) \
      _Pragma("unroll") for (int k = 1; k < 8; ++k) ev[8*c+k] += ev[8*c+k-1]; \
    { float Te = (ev[7]+ev[15]) + (ev[23]+ev[31]); \
      float v_ = wscan_add(Te); \
      float exw = fmaxf(v_ - Te, 0.f); \
      float S = __shfl(v_, 63); \
      float f0 = exw, f1 = f0+ev[7], f2 = f1+ev[15], f3 = f2+ev[23]; \
      _Pragma("unroll") for (int k = 0; k < 8; ++k) { \
        ev[k]    = __builtin_amdgcn_logf(fmaxf(ev[k]    + f0, 1e-30f)); \
        ev[8+k]  = __builtin_amdgcn_logf(fmaxf(ev[8+k]  + f1, 1e-30f)); \
        ev[16+k] = __builtin_amdgcn_logf(fmaxf(ev[16+k] + f2, 1e-30f)); \
        ev[24+k] = __builtin_amdgcn_logf(fmaxf(ev[24+k] + f3, 1e-30f)); } \
      { float* op = AO + (size_t)r_ * M_ + c0; \
        _Pragma("unroll") for (int g = 0; g < 8; ++g) { \
          float4 o_; \
          o_.x = __builtin_fmaf(ev[4*g+0], LN2, le[BUF][4*g+0] + Cv); \
          o_.y = __builtin_fmaf(ev[4*g+1], LN2, le[BUF][4*g+1] + Cv); \
          o_.z = __builtin_fmaf(ev[4*g+2], LN2, le[BUF][4*g+2] + Cv); \
          o_.w = __builtin_fmaf(ev[4*g+3], LN2, le[BUF][4*g+3] + Cv); \
          *(float4*)(op + 4*g) = o_; } } \
      _Pragma("unroll") for (int e = 0; e < 32; ++e) \
        ww[e] = __builtin_fmaf(le[BUF][e], L2E, ev[e]); \
      { float lgS = __builtin_amdgcn_logf(fmaxf(S, 1e-30f)); \
        dC2p = -lgS - TWO_D2; \
        Cv = __builtin_fmaf(lgS, LN2, Cv + MLn); } } \
    { const int rp = (r_ + 2 < T_) ? r_ + 2 : T_ - 1; ALD(BUF, rp) } \
    __builtin_amdgcn_sched_barrier(0); \
  }

    for (int r = 0; r < T_; r += 2) {
      ASTEP(0, r)
      ASTEP(1, r + 1)
    }
  } else {
    // ======================= beta (reversed frame) =======================
    float* BO = beta_out + (size_t)b * T_ * M_;
    const int jb = M_ - 32 - c0;   // element e <-> column j = jb + 31 - e

#define BLD(BUF, R) { const float* p_ = LE + (size_t)(R) * M_ + jb; \
    _Pragma("unroll") for (int g = 0; g < 8; ++g) { \
      float4 v_ = *(const float4*)(p_ + 4*g); \
      le[BUF][31-4*g]=v_.x; le[BUF][30-4*g]=v_.y; le[BUF][29-4*g]=v_.z; le[BUF][28-4*g]=v_.w; } }

    // init row T-1: zeros, 1.0 at j = M-1 (faithful odd init)
    { float* op = BO + (size_t)(T_ - 1) * M_ + jb;
      float4 z4 = make_float4(0.f, 0.f, 0.f, 0.f);
#pragma unroll
      for (int g = 0; g < 7; ++g) *(float4*)(op + 4*g) = z4;
      *(float4*)(op + 28) = make_float4(0.f, 0.f, 0.f, (lane == 0) ? 1.f : 0.f);
    }

    BLD(0, T_ - 2) BLD(1, T_ - 3)
    Cv   = 14.8155f * invT + 1.5f;
    dC2p = -Cv * L2E;
#pragma unroll
    for (int e = 0; e < 32; ++e) ww[e] = 0.f;
    if (lane == 0) ww[0] = L2E;   // beta_{T-1}[M-1] = 1.0 (log-domain, faithful)

#define BSTEP(BUF, TT) { \
    const int t_ = (TT); \
    _Pragma("unroll") for (int e = 0; e < 32; ++e) \
      ev[e] = __builtin_amdgcn_exp2f(__builtin_fmaf(le[BUF][e], L2E, ww[e] + dC2p)); \
    _Pragma("unroll") for (int e = 0; e < 32; ++e) \
      tt[e] = __builtin_amdgcn_exp2f(__builtin_fmaf(le[BUF][e], L2E, -D2)); \
    { const int tp = (t_ - 2 >= 0) ? t_ - 2 : 0; BLD(BUF, tp) } \
    __builtin_amdgcn_sched_barrier(0); \
    _Pragma("unroll") for (int c = 0; c < 4; ++c) \
      _Pragma("unroll") for (int k = 1; k < 8; ++k) tt[8*c+k] += tt[8*c+k-1]; \
    { float Tt = (tt[7]+tt[15]) + (tt[23]+tt[31]); \
      float vt = wscan_add(Tt); \
      float ext = fmaxf(vt - Tt, 0.f); \
      float g0 = ext, g1 = g0+tt[7], g2 = g1+tt[15], g3 = g2+tt[23]; \
      _Pragma("unroll") for (int k = 0; k < 8; ++k) { \
        tt[k]    = __builtin_amdgcn_logf(tt[k]    + g0); \
        tt[8+k]  = __builtin_amdgcn_logf(tt[8+k]  + g1); \
        tt[16+k] = __builtin_amdgcn_logf(tt[16+k] + g2); \
        tt[24+k] = __builtin_amdgcn_logf(tt[24+k] + g3); } } \
    _Pragma("unroll") for (int c = 0; c < 4; ++c) \
      _Pragma("unroll") for (int k = 1; k < 8; ++k) ev[8*c+k] += ev[8*c+k-1]; \
    { float Te = (ev[7]+ev[15]) + (ev[23]+ev[31]); \
      float v_ = wscan_add(Te); \
      float exw = fmaxf(v_ - Te, 0.f); \
      float S = __shfl(v_, 63); \
      float f0 = exw, f1 = f0+ev[7], f2 = f1+ev[15], f3 = f2+ev[23]; \
      _Pragma("unroll") for (int k = 0; k < 8; ++k) { \
        ev[k]    = __builtin_amdgcn_logf(fmaxf(ev[k]    + f0, 1e-30f)); \
        ev[8+k]  = __builtin_amdgcn_logf(fmaxf(ev[8+k]  + f1, 1e-30f)); \
        ev[16+k] = __builtin_amdgcn_logf(fmaxf(ev[16+k] + f2, 1e-30f)); \
        ev[24+k] = __builtin_amdgcn_logf(fmaxf(ev[24+k] + f3, 1e-30f)); } \
      _Pragma("unroll") for (int e = 0; e < 32; ++e) \
        ww[e] = (ev[e] - tt[e]) - D2; \
      { float* op = BO + (size_t)t_ * M_ + jb; \
        _Pragma("unroll") for (int g = 0; g < 8; ++g) { \
          float4 o_; \
          o_.x = __builtin_fmaf(ww[31-4*g], LN2, Cv); \
          o_.y = __builtin_fmaf(ww[30-4*g], LN2, Cv); \
          o_.z = __builtin_fmaf(ww[29-4*g], LN2, Cv); \
          o_.w = __builtin_fmaf(ww[28-4*g], LN2, Cv); \
          *(float4*)(op + 4*g) = o_; } } \
      { float lgS = __builtin_amdgcn_logf(fmaxf(S, 1e-30f)); \
        dC2p = -lgS - KB2; \
        Cv = __builtin_fmaf(lgS, LN2, Cv + KB); } } \
    __builtin_amdgcn_sched_barrier(0); \
  }

    for (int t = T_ - 2; t >= 0; t -= 2) {
      BSTEP(0, t)
      if (t > 0) BSTEP(1, t - 1)
    }
  }
}

// ---------------------------------------------------------------------------
// K6: gamma = (t<=m) ? alpha+beta : NEGV; LSE over t; single global read:
//     bf16 gamma stashed in LDS; pass2 writes gamma_log (in-place over alpha)
//     and gammaT[b,m,t] (mask recomputed; bf16 only touches finite values).
// ---------------------------------------------------------------------------
__launch_bounds__(256)
__global__ void k6_combine(float* __restrict__ alpha_gl, const float* __restrict__ beta,
                           u16* __restrict__ gammaT)
{
  __shared__ u16 gst[32][514];
  __shared__ float smx[8][32], ssm[8][32];
  const int b  = blockIdx.x >> 6;
  const int m0 = (blockIdx.x & 63) * 32;
  const int tid = threadIdx.x;
  const int mi = tid & 31, ti = tid >> 5;
  const int m = m0 + mi;
  const size_t base = (size_t)b * T_ * M_ + m;

  float mx = -3.0e38f, s = 0.f;
  for (int t = ti; t < T_; t += 8) {
    float a  = alpha_gl[base + (size_t)t * M_];
    float bt = beta[base + (size_t)t * M_];
    float g = (t <= m) ? (a + bt) : NEGV;
    gst[mi][t] = f2bf(g);
    if (g > mx) { s = s * __builtin_amdgcn_exp2f((mx - g) * L2E) + 1.f; mx = g; }
    else        { s += __builtin_amdgcn_exp2f((g - mx) * L2E); }
  }
  smx[ti][mi] = mx; ssm[ti][mi] = s;
  __syncthreads();
  float Mv = smx[0][mi], Sv = ssm[0][mi];
#pragma unroll
  for (int k = 1; k < 8; ++k) {
    float Mk = smx[k][mi], Sk = ssm[k][mi];
    if (Mk > Mv) { Sv = Sv * __builtin_amdgcn_exp2f((Mv - Mk) * L2E) + Sk; Mv = Mk; }
    else         { Sv += Sk * __builtin_amdgcn_exp2f((Mk - Mv) * L2E); }
  }
  const float lse = Mv + LN2 * __builtin_amdgcn_logf(Sv);

  // pass2a: gamma_log (f32) in place over alpha
  for (int t = ti; t < T_; t += 8) {
    float g = (t <= m) ? bf2f(gst[mi][t]) : NEGV;
    alpha_gl[base + (size_t)t * M_] = g - lse;
  }
  // pass2b: gammaT[b, m0+k, t] from LDS stash (coalesced u32 rows)
  for (int k = 0; k < 32; ++k) {
    u32 val = *(const u32*)&gst[k][2 * tid];
    int mr = m0 + k;
    u32 lo = (2 * tid     <= mr) ? (val & 0x0000FFFFu) : 0u;
    u32 hi = (2 * tid + 1 <= mr) ? (val & 0xFFFF0000u) : 0u;
    ((u32*)gammaT)[((((size_t)b * M_ + m0 + k) * T_) >> 1) + tid] = lo | hi;
  }
}

// ---------------------------------------------------------------------------
// K7: expanded[b,m,c] = sum_t gammaT[m,t]*textT[c,t]  + (-1e30)*suffix[m+1,c]
// ---------------------------------------------------------------------------
__launch_bounds__(256)
__global__ void k7_expanded(const u16* __restrict__ gammaT, const u16* __restrict__ textT,
                            const float* __restrict__ suffix, float* __restrict__ expanded)
{
  __shared__ __align__(16) short As[128][40];
  __shared__ __align__(16) short Bs[128][40];
  const int b   = blockIdx.z;
  const int m0  = blockIdx.x * 128;
  const int c0  = blockIdx.y * 128;
  const int tid = threadIdx.x;
  const int lane = tid & 63, wid = tid >> 6;
  const int wr = wid >> 1, wc = wid & 1;
  const u16* Ab = gammaT + (size_t)b * M_ * T_;
  const u16* Bb = textT  + (size_t)b * C_ * T_;
  f32x4 acc[4][4];
#pragma unroll
  for (int i = 0; i < 4; ++i)
#pragma unroll
    for (int j = 0; j < 4; ++j) acc[i][j] = (f32x4){0.f, 0.f, 0.f, 0.f};

  const int ko  = (tid & 3) * 8;
  const int rb2 = tid >> 2;
  for (int kk = 0; kk < T_; kk += 32) {
    __syncthreads();
#pragma unroll
    for (int it = 0; it < 2; ++it) {
      int r = rb2 + it * 64;
      *(uint4*)&As[r][ko] = *(const uint4*)(Ab + (size_t)(m0 + r) * T_ + kk + ko);
      *(uint4*)&Bs[r][ko] = *(const uint4*)(Bb + (size_t)(c0 + r) * T_ + kk + ko);
    }
    __syncthreads();
    const int k0 = (lane >> 4) * 8;
    bf16x8 af[4], bfr[4];
#pragma unroll
    for (int i = 0; i < 4; ++i) {
      af[i]  = *(const bf16x8*)&As[wr * 64 + i * 16 + (lane & 15)][k0];
      bfr[i] = *(const bf16x8*)&Bs[wc * 64 + i * 16 + (lane & 15)][k0];
    }
#pragma unroll
    for (int i = 0; i < 4; ++i)
#pragma unroll
      for (int j = 0; j < 4; ++j)
        acc[i][j] = __builtin_amdgcn_mfma_f32_16x16x32_bf16(af[i], bfr[j], acc[i][j], 0, 0, 0);
  }
#pragma unroll
  for (int i = 0; i < 4; ++i) {
#pragma unroll
    for (int j = 0; j < 4; ++j) {
#pragma unroll
      for (int rr = 0; rr < 4; ++rr) {
        int m = m0 + wr * 64 + i * 16 + (lane >> 4) * 4 + rr;
        int c = c0 + wc * 64 + j * 16 + (lane & 15);
        int sidx = (m + 1 < T_) ? (m + 1) : T_;
        float sfx = suffix[((size_t)b * (T_ + 1) + sidx) * C_ + c];
        expanded[((size_t)b * M_ + m) * C_ + c] = acc[i][j][rr] + NEGV * sfx;
      }
    }
  }
}

// ---------------------------------------------------------------------------
extern "C" void kernel_launch(void* const* d_in, const int* in_sizes, int n_in,
                              void* d_out, int out_size, void* d_ws, size_t ws_size,
                              hipStream_t stream) {
  const float* text  = (const float*)d_in[0];
  const float* mel   = (const float*)d_in[1];
  const float* noise = (const float*)d_in[2];
  const float* ratio = (const float*)d_in[3];

  const size_t BTM = (size_t)B_ * T_ * M_;   // 16777216
  float* out       = (float*)d_out;
  float* gamma_log = out;                    // also alpha scratch
  float* expanded  = out + BTM;              // also beta scratch

  char* w = (char*)d_ws;
  float* log_e  = (float*)(w + 0);           // 67108864 B
  float* suffix = (float*)(w + 67108864);    // [B][T+1][C]  16809984 B
  u16*   textT  = (u16*)  (w + 83918848);    // [B][C][T]     8388608 B
  u16*   gammaT = (u16*)  (w + 92307456);    // [B][M][T]    33554432 B
  float* partial = (float*)(w + 0);          // k3 scratch, reuses log_e region (before k1)

  k3a_partial<<<B_ * 8,          512, 0, stream>>>(text, partial);
  k3b_suffix <<<B_ * 8,          512, 0, stream>>>(text, partial, suffix);
  k3t_textT  <<<dim3(8, 8, 16),  256, 0, stream>>>(text, textT);
  k1_energy  <<<dim3(4, 16, 16), 256, 0, stream>>>(text, mel, noise, ratio, log_e);
  k4_dp      <<<32,               64, 0, stream>>>(log_e, ratio, gamma_log, expanded);
  k6_combine <<<B_ * 64,         256, 0, stream>>>(gamma_log, expanded, gammaT);
  k7_expanded<<<dim3(16, 4, 16), 256, 0, stream>>>(gammaT, textT, suffix, expanded);
}

// Round 5
// 576.643 us; speedup vs baseline: 1.4192x; 1.4192x over previous
//
#include <hip/hip_runtime.h>

#define B_  16
#define T_  512
#define M_  2048
#define C_  512
#define NEGV (-1e30f)
#define L2E 1.4426950408889634f
#define LN2 0.69314718055994531f

typedef unsigned short u16;
typedef unsigned int   u32;
using bf16x8 = __attribute__((ext_vector_type(8))) short;
using f32x4  = __attribute__((ext_vector_type(4))) float;

__device__ __forceinline__ u16 f2bf(float x) {
  u32 u = __float_as_uint(x);
  return (u16)((u + 0x7FFFu + ((u >> 16) & 1u)) >> 16);
}
__device__ __forceinline__ float bf2f(u16 u) {
  return __uint_as_float(((u32)u) << 16);
}
__device__ __forceinline__ float rdlane63(float x) {
  return __int_as_float(__builtin_amdgcn_readlane(__float_as_int(x), 63));
}

// 64-lane inclusive add-scan via DPP (row_shr 1/2/4/8, bcast15, bcast31)
__device__ __forceinline__ float wscan_add(float x) {
  x += __int_as_float(__builtin_amdgcn_update_dpp(0, __float_as_int(x), 0x111, 0xF, 0xF, true));
  x += __int_as_float(__builtin_amdgcn_update_dpp(0, __float_as_int(x), 0x112, 0xF, 0xF, true));
  x += __int_as_float(__builtin_amdgcn_update_dpp(0, __float_as_int(x), 0x114, 0xF, 0xF, true));
  x += __int_as_float(__builtin_amdgcn_update_dpp(0, __float_as_int(x), 0x118, 0xF, 0xF, true));
  x += __int_as_float(__builtin_amdgcn_update_dpp(0, __float_as_int(x), 0x142, 0xA, 0xF, true));
  x += __int_as_float(__builtin_amdgcn_update_dpp(0, __float_as_int(x), 0x143, 0xC, 0xF, true));
  return x;
}

// ---------------------------------------------------------------------------
// K1: energy GEMM (bf16 MFMA) + gumbel + /temperature -> tt = exp(le - D) bf16
// ---------------------------------------------------------------------------
__launch_bounds__(256)
__global__ void k1_energy(const float* __restrict__ text, const float* __restrict__ mel,
                          const float* __restrict__ noise, const float* __restrict__ ratio,
                          u16* __restrict__ ttbuf)
{
  __shared__ __align__(16) short As[128][40];
  __shared__ __align__(16) short Bs[128][40];
  const int b   = blockIdx.z;
  const int t0  = blockIdx.x * 128;
  const int m0  = blockIdx.y * 128;
  const int tid = threadIdx.x;
  const int lane = tid & 63, wid = tid >> 6;
  const int wr = wid >> 1, wc = wid & 1;
  const float* Ab = text + (size_t)b * T_ * C_;
  const float* Bb = mel  + (size_t)b * M_ * C_;
  f32x4 acc[4][4];
#pragma unroll
  for (int i = 0; i < 4; ++i)
#pragma unroll
    for (int j = 0; j < 4; ++j) acc[i][j] = (f32x4){0.f, 0.f, 0.f, 0.f};

  const int kq = (tid & 7) * 4;
  const int rb = tid >> 3;
  for (int kk = 0; kk < C_; kk += 32) {
    __syncthreads();
#pragma unroll
    for (int it = 0; it < 4; ++it) {
      int r = rb + it * 32;
      float4 va = *(const float4*)(Ab + (size_t)(t0 + r) * C_ + kk + kq);
      As[r][kq + 0] = (short)f2bf(va.x); As[r][kq + 1] = (short)f2bf(va.y);
      As[r][kq + 2] = (short)f2bf(va.z); As[r][kq + 3] = (short)f2bf(va.w);
      float4 vb = *(const float4*)(Bb + (size_t)(m0 + r) * C_ + kk + kq);
      Bs[r][kq + 0] = (short)f2bf(vb.x); Bs[r][kq + 1] = (short)f2bf(vb.y);
      Bs[r][kq + 2] = (short)f2bf(vb.z); Bs[r][kq + 3] = (short)f2bf(vb.w);
    }
    __syncthreads();
    const int k0 = (lane >> 4) * 8;
    bf16x8 af[4], bfr[4];
#pragma unroll
    for (int i = 0; i < 4; ++i) {
      af[i]  = *(const bf16x8*)&As[wr * 64 + i * 16 + (lane & 15)][k0];
      bfr[i] = *(const bf16x8*)&Bs[wc * 64 + i * 16 + (lane & 15)][k0];
    }
#pragma unroll
    for (int i = 0; i < 4; ++i)
#pragma unroll
      for (int j = 0; j < 4; ++j)
        acc[i][j] = __builtin_amdgcn_mfma_f32_16x16x32_bf16(af[i], bfr[j], acc[i][j], 0, 0, 0);
  }
  const float invT = 1.0f / (0.1f + 0.9f * ratio[0]);
  const float D2 = 14.5f * invT * L2E;
#pragma unroll
  for (int i = 0; i < 4; ++i) {
#pragma unroll
    for (int j = 0; j < 4; ++j) {
#pragma unroll
      for (int rr = 0; rr < 4; ++rr) {
        int t = t0 + wr * 64 + i * 16 + (lane >> 4) * 4 + rr;
        int m = m0 + wc * 64 + j * 16 + (lane & 15);
        size_t idx = ((size_t)b * T_ + t) * M_ + m;
        float en = acc[i][j][rr] * (1.0f / 512.0f);
        float u  = noise[idx];
        float nl = -LN2 * __builtin_amdgcn_logf(u);    // -ln u  (>0)
        float g  = -LN2 * __builtin_amdgcn_logf(nl);   // -ln(-ln u)
        float le = (en + g) * invT;
        float tv = __builtin_amdgcn_exp2f(__builtin_fmaf(le, L2E, -D2));
        ttbuf[idx] = f2bf(tv);
      }
    }
  }
}

// ---------------------------------------------------------------------------
// K3a: per-chunk partial sums of text over t (chunk = 64 rows)
// ---------------------------------------------------------------------------
__launch_bounds__(512)
__global__ void k3a_partial(const float* __restrict__ text, float* __restrict__ partial)
{
  const int b = blockIdx.x >> 3, ch = blockIdx.x & 7, c = threadIdx.x;
  const float* tb = text + (size_t)b * T_ * C_ + (size_t)ch * 64 * C_ + c;
  float s = 0.f;
#pragma unroll 8
  for (int tt = 0; tt < 64; ++tt) s += tb[(size_t)tt * C_];
  partial[((size_t)b * 8 + ch) * C_ + c] = s;
}

// ---------------------------------------------------------------------------
// K3b: suffix[b,t,c] = sum_{t'>=t} text[b,t',c]; layout [B][T+1][C], row T = 0
// ---------------------------------------------------------------------------
__launch_bounds__(512)
__global__ void k3b_suffix(const float* __restrict__ text, const float* __restrict__ partial,
                           float* __restrict__ suffix)
{
  const int b = blockIdx.x >> 3, ch = blockIdx.x & 7, c = threadIdx.x;
  float off = 0.f;
  for (int ch2 = ch + 1; ch2 < 8; ++ch2) off += partial[((size_t)b * 8 + ch2) * C_ + c];
  const float* tb = text + (size_t)b * T_ * C_ + (size_t)ch * 64 * C_ + c;
  float* sb = suffix + (size_t)b * (T_ + 1) * C_ + (size_t)ch * 64 * C_ + c;
  if (ch == 7) sb[(size_t)64 * C_] = 0.f;   // row T_
  float s = off;
  for (int tt = 63; tt >= 0; --tt) {
    s += tb[(size_t)tt * C_];
    sb[(size_t)tt * C_] = s;
  }
}

// ---------------------------------------------------------------------------
// K3t: textT[b,c,t] = bf16(text[b,t,c])  (LDS transpose tiles)
// ---------------------------------------------------------------------------
__launch_bounds__(256)
__global__ void k3t_textT(const float* __restrict__ text, u16* __restrict__ textT)
{
  __shared__ u16 tile[64][66];
  const int b  = blockIdx.z;
  const int t0 = blockIdx.x * 64;
  const int c0 = blockIdx.y * 64;
  const int tid = threadIdx.x;
  const int j = tid & 63, i4 = tid >> 6;
#pragma unroll
  for (int it = 0; it < 16; ++it) {
    int i = it * 4 + i4;
    tile[i][j] = f2bf(text[((size_t)b * T_ + t0 + i) * C_ + c0 + j]);
  }
  __syncthreads();
#pragma unroll
  for (int it = 0; it < 16; ++it) {
    int cc = it * 4 + i4;
    textT[((size_t)b * C_ + c0 + cc) * T_ + t0 + j] = tile[j][cc];
  }
}

// ---------------------------------------------------------------------------
// K4: alpha (blocks 0..15) / beta (blocks 16..31). ONE WAVE per chain.
//     LINEAR-domain DP: carries A = exp(alpha - C) in registers; per step only
//     32 rcp + 1 log. tt = exp(le - D) loaded bf16 (k1). Outputs A/B as bf16
//     + per-row scale CA/CB; k6 does the logs. 4-deep raw-dword prefetch.
// ---------------------------------------------------------------------------
__launch_bounds__(64, 1)
__global__ void k4_dp(const u16* __restrict__ ttbuf,
                      u16* __restrict__ Abuf, u16* __restrict__ Bbuf,
                      float* __restrict__ CAa, float* __restrict__ CBa)
{
  const int blk = blockIdx.x;
  const int b   = blk & 15;
  const int lane = threadIdx.x & 63;
  const u16* TT = ttbuf + (size_t)b * T_ * M_;
  uint4 raw[4][4];
  float tt[32], cum[32], A[32];
  float Cv = 0.f;

  if (blk < 16) {
    // ======================= alpha =======================
    const int c0 = lane * 32;
    u16* AO = Abuf + (size_t)b * T_ * M_;
    float* CO = CAa + (size_t)b * T_;

#define TLDA(BUF, R) { const uint4* p_ = (const uint4*)(TT + (size_t)(R) * M_ + c0); \
    raw[BUF][0] = p_[0]; raw[BUF][1] = p_[1]; raw[BUF][2] = p_[2]; raw[BUF][3] = p_[3]; }

#define UNPKA(BUF) { \
    _Pragma("unroll") for (int q = 0; q < 4; ++q) { \
      u32 w0 = raw[BUF][q].x, w1 = raw[BUF][q].y, w2 = raw[BUF][q].z, w3 = raw[BUF][q].w; \
      tt[8*q+0] = __uint_as_float(w0 << 16); tt[8*q+1] = __uint_as_float(w0 & 0xFFFF0000u); \
      tt[8*q+2] = __uint_as_float(w1 << 16); tt[8*q+3] = __uint_as_float(w1 & 0xFFFF0000u); \
      tt[8*q+4] = __uint_as_float(w2 << 16); tt[8*q+5] = __uint_as_float(w2 & 0xFFFF0000u); \
      tt[8*q+6] = __uint_as_float(w3 << 16); tt[8*q+7] = __uint_as_float(w3 & 0xFFFF0000u); } }

#define ASTEP(BUF, PBUF, R) { \
    const int r_ = (R); \
    TLDA(PBUF, (r_ + 3 < T_) ? r_ + 3 : T_ - 1) \
    __builtin_amdgcn_sched_barrier(0); \
    UNPKA(BUF) \
    /* suffix cumsum of tt -> cum (= Srow scaled) */ \
    _Pragma("unroll") for (int c = 0; c < 4; ++c) { \
      cum[8*c+7] = tt[8*c+7]; \
      _Pragma("unroll") for (int k = 6; k >= 0; --k) cum[8*c+k] = tt[8*c+k] + cum[8*c+k+1]; } \
    { float lt = (cum[0] + cum[8]) + (cum[16] + cum[24]); \
      float incl = wscan_add(lt); \
      float Tot = rdlane63(incl); \
      float crs = Tot - incl; \
      float s3 = crs, s2 = cum[24]+s3, s1 = cum[16]+s2, s0 = cum[8]+s1; \
      _Pragma("unroll") for (int k = 0; k < 8; ++k) { \
        cum[k] += s0; cum[8+k] += s1; cum[16+k] += s2; cum[24+k] += s3; } } \
    _Pragma("unroll") for (int e = 0; e < 32; ++e) cum[e] = __builtin_amdgcn_rcpf(cum[e]); \
    { float a31 = __shfl_up(A[31], 1); \
      float am1 = (lane == 0) ? ((r_ == 0) ? 1.f : 0.f) : a31; \
      cum[0] *= am1; \
      _Pragma("unroll") for (int e = 31; e >= 1; --e) cum[e] *= A[e-1]; } \
    /* prefix cumsum of u -> P */ \
    _Pragma("unroll") for (int c = 0; c < 4; ++c) \
      _Pragma("unroll") for (int k = 1; k < 8; ++k) cum[8*c+k] += cum[8*c+k-1]; \
    { float Te = (cum[7] + cum[15]) + (cum[23] + cum[31]); \
      float v_ = wscan_add(Te); \
      float exw = v_ - Te; \
      float Zt = rdlane63(v_); \
      float f0 = exw, f1 = f0+cum[7], f2 = f1+cum[15], f3 = f2+cum[23]; \
      _Pragma("unroll") for (int k = 0; k < 8; ++k) { \
        cum[k] += f0; cum[8+k] += f1; cum[16+k] += f2; cum[24+k] += f3; } \
      float Zc = fmaxf(Zt, 1e-35f); \
      float zr = __builtin_amdgcn_rcpf(Zc); \
      Cv += LN2 * __builtin_amdgcn_logf(Zc); \
      if (lane == 0) CO[r_] = Cv; \
      _Pragma("unroll") for (int e = 0; e < 32; ++e) A[e] = tt[e] * cum[e] * zr; } \
    { u32 w_[16]; \
      _Pragma("unroll") for (int d = 0; d < 16; ++d) \
        w_[d] = __builtin_amdgcn_perm(__float_as_uint(A[2*d+1]), __float_as_uint(A[2*d]), 0x07060302u); \
      uint4* op = (uint4*)(AO + (size_t)r_ * M_ + c0); \
      op[0] = make_uint4(w_[0],w_[1],w_[2],w_[3]); \
      op[1] = make_uint4(w_[4],w_[5],w_[6],w_[7]); \
      op[2] = make_uint4(w_[8],w_[9],w_[10],w_[11]); \
      op[3] = make_uint4(w_[12],w_[13],w_[14],w_[15]); } \
  }

#pragma unroll
    for (int e = 0; e < 32; ++e) A[e] = 0.f;
    TLDA(0, 0) TLDA(1, 1) TLDA(2, 2)
    for (int r = 0; r < T_; r += 4) {
      ASTEP(0, 3, r)
      ASTEP(1, 0, r + 1)
      ASTEP(2, 1, r + 2)
      ASTEP(3, 2, r + 3)
    }
  } else {
    // ======================= beta (reversed frame) =======================
    const int jb = M_ - 32 - lane * 32;     // element e <-> column j = jb + 31 - e
    u16* BO = Bbuf + (size_t)b * T_ * M_;
    float* CO = CBa + (size_t)b * T_;

#define TLDB(BUF, R) { const uint4* p_ = (const uint4*)(TT + (size_t)(R) * M_ + jb); \
    raw[BUF][0] = p_[0]; raw[BUF][1] = p_[1]; raw[BUF][2] = p_[2]; raw[BUF][3] = p_[3]; }

#define UNPKB(BUF) { \
    _Pragma("unroll") for (int q = 0; q < 4; ++q) { \
      u32 w0 = raw[BUF][q].x, w1 = raw[BUF][q].y, w2 = raw[BUF][q].z, w3 = raw[BUF][q].w; \
      tt[31-8*q] = __uint_as_float(w0 << 16); tt[30-8*q] = __uint_as_float(w0 & 0xFFFF0000u); \
      tt[29-8*q] = __uint_as_float(w1 << 16); tt[28-8*q] = __uint_as_float(w1 & 0xFFFF0000u); \
      tt[27-8*q] = __uint_as_float(w2 << 16); tt[26-8*q] = __uint_as_float(w2 & 0xFFFF0000u); \
      tt[25-8*q] = __uint_as_float(w3 << 16); tt[24-8*q] = __uint_as_float(w3 & 0xFFFF0000u); } }

#define BSTEP(BUF, PBUF, I) { \
    const int t_ = (T_ - 2) - (I); \
    { int tp_ = t_ - 3; if (tp_ < 0) tp_ = 0; TLDB(PBUF, tp_) } \
    __builtin_amdgcn_sched_barrier(0); \
    UNPKB(BUF) \
    _Pragma("unroll") for (int e = 0; e < 32; ++e) cum[e] = A[e] * tt[e]; \
    /* prefix cumsum of tt in place (= Srow scaled, reversed frame) */ \
    _Pragma("unroll") for (int c = 0; c < 4; ++c) \
      _Pragma("unroll") for (int k = 1; k < 8; ++k) tt[8*c+k] += tt[8*c+k-1]; \
    { float Tt = (tt[7] + tt[15]) + (tt[23] + tt[31]); \
      float vt = wscan_add(Tt); \
      float ext = vt - Tt; \
      float g0 = ext, g1 = g0+tt[7], g2 = g1+tt[15], g3 = g2+tt[23]; \
      _Pragma("unroll") for (int k = 0; k < 8; ++k) { \
        tt[k] += g0; tt[8+k] += g1; tt[16+k] += g2; tt[24+k] += g3; } } \
    /* prefix cumsum of q -> Q */ \
    _Pragma("unroll") for (int c = 0; c < 4; ++c) \
      _Pragma("unroll") for (int k = 1; k < 8; ++k) cum[8*c+k] += cum[8*c+k-1]; \
    { float Te = (cum[7] + cum[15]) + (cum[23] + cum[31]); \
      float v_ = wscan_add(Te); \
      float exw = v_ - Te; \
      float Zb = rdlane63(v_); \
      float f0 = exw, f1 = f0+cum[7], f2 = f1+cum[15], f3 = f2+cum[23]; \
      _Pragma("unroll") for (int k = 0; k < 8; ++k) { \
        cum[k] += f0; cum[8+k] += f1; cum[16+k] += f2; cum[24+k] += f3; } \
      float Zc = fmaxf(Zb, 1e-35f); \
      float zr = __builtin_amdgcn_rcpf(Zc); \
      Cv += LN2 * __builtin_amdgcn_logf(Zc); \
      _Pragma("unroll") for (int e = 0; e < 32; ++e) \
        A[e] = cum[e] * __builtin_amdgcn_rcpf(tt[e]) * zr; \
      if (t_ >= 0) { \
        if (lane == 0) CO[t_] = Cv; \
        u32 w_[16]; \
        _Pragma("unroll") for (int d = 0; d < 16; ++d) \
          w_[d] = __builtin_amdgcn_perm(__float_as_uint(A[30-2*d]), __float_as_uint(A[31-2*d]), 0x07060302u); \
        uint4* op = (uint4*)(BO + (size_t)t_ * M_ + jb); \
        op[0] = make_uint4(w_[0],w_[1],w_[2],w_[3]); \
        op[1] = make_uint4(w_[4],w_[5],w_[6],w_[7]); \
        op[2] = make_uint4(w_[8],w_[9],w_[10],w_[11]); \
        op[3] = make_uint4(w_[12],w_[13],w_[14],w_[15]); } \
    } \
  }

    // init row T-1: beta=0 -> B=1 everywhere; +1.0 at j=M-1 -> B=e (faithful)
#pragma unroll
    for (int e = 0; e < 32; ++e) A[e] = 1.f;
    if (lane == 0) A[0] = 2.718281828f;
    { u32 w_[16];
#pragma unroll
      for (int d = 0; d < 16; ++d)
        w_[d] = __builtin_amdgcn_perm(__float_as_uint(A[30-2*d]), __float_as_uint(A[31-2*d]), 0x07060302u);
      uint4* op = (uint4*)(BO + (size_t)(T_ - 1) * M_ + jb);
      op[0] = make_uint4(w_[0],w_[1],w_[2],w_[3]);
      op[1] = make_uint4(w_[4],w_[5],w_[6],w_[7]);
      op[2] = make_uint4(w_[8],w_[9],w_[10],w_[11]);
      op[3] = make_uint4(w_[12],w_[13],w_[14],w_[15]);
      if (lane == 0) CO[T_ - 1] = 0.f;
    }
    TLDB(0, T_ - 2) TLDB(1, T_ - 3) TLDB(2, T_ - 4)
    for (int i = 0; i < 512; i += 4) {
      BSTEP(0, 3, i)
      BSTEP(1, 0, i + 1)
      BSTEP(2, 1, i + 2)
      BSTEP(3, 2, i + 3)
    }
  }
}

// ---------------------------------------------------------------------------
// K6: gamma = (t<=m) ? LN2*(log2 A + log2 B) + CA[t]+CB[t] : NEGV  (clamped);
//     LSE over t; gamma_log -> d_out; gammaT bf16 (masked) via LDS stash.
// ---------------------------------------------------------------------------
__launch_bounds__(256)
__global__ void k6_combine(const u16* __restrict__ Abuf, const u16* __restrict__ Bbuf,
                           const float* __restrict__ CAa, const float* __restrict__ CBa,
                           float* __restrict__ gamma_log, u16* __restrict__ gammaT)
{
  __shared__ u16 gst[32][514];
  __shared__ float cd[T_];
  __shared__ float smx[8][32], ssm[8][32];
  const int b  = blockIdx.x >> 6;
  const int m0 = (blockIdx.x & 63) * 32;
  const int tid = threadIdx.x;
  const int mi = tid & 31, ti = tid >> 5;
  const int m = m0 + mi;
  const size_t base = (size_t)b * T_ * M_ + m;

  cd[tid]       = CAa[b * T_ + tid]       + CBa[b * T_ + tid];
  cd[tid + 256] = CAa[b * T_ + tid + 256] + CBa[b * T_ + tid + 256];
  __syncthreads();

  float mx = -3.0e38f, s = 0.f;
  for (int t = ti; t < T_; t += 8) {
    float a  = bf2f(Abuf[base + (size_t)t * M_]);
    float bb = bf2f(Bbuf[base + (size_t)t * M_]);
    float g;
    if (t <= m) {
      g = __builtin_fmaf(__builtin_amdgcn_logf(a) + __builtin_amdgcn_logf(bb), LN2, cd[t]);
      g = fmaxf(g, -1e8f);            // underflow clamp (error << thresholds)
    } else g = NEGV;
    gst[mi][t] = f2bf(g);
    if (g > mx) { s = s * __builtin_amdgcn_exp2f((mx - g) * L2E) + 1.f; mx = g; }
    else        { s += __builtin_amdgcn_exp2f((g - mx) * L2E); }
  }
  smx[ti][mi] = mx; ssm[ti][mi] = s;
  __syncthreads();
  float Mv = smx[0][mi], Sv = ssm[0][mi];
#pragma unroll
  for (int k = 1; k < 8; ++k) {
    float Mk = smx[k][mi], Sk = ssm[k][mi];
    if (Mk > Mv) { Sv = Sv * __builtin_amdgcn_exp2f((Mv - Mk) * L2E) + Sk; Mv = Mk; }
    else         { Sv += Sk * __builtin_amdgcn_exp2f((Mk - Mv) * L2E); }
  }
  const float lse = Mv + LN2 * __builtin_amdgcn_logf(Sv);

  // pass2a: gamma_log (masked entries exact NEGV, not bf16-rounded)
  for (int t = ti; t < T_; t += 8) {
    float g = (t <= m) ? bf2f(gst[mi][t]) : NEGV;
    gamma_log[base + (size_t)t * M_] = g - lse;
  }
  // pass2b: gammaT[b, m0+k, t] from LDS stash (coalesced u32 rows)
  for (int k = 0; k < 32; ++k) {
    u32 val = *(const u32*)&gst[k][2 * tid];
    int mr = m0 + k;
    u32 lo = (2 * tid     <= mr) ? (val & 0x0000FFFFu) : 0u;
    u32 hi = (2 * tid + 1 <= mr) ? (val & 0xFFFF0000u) : 0u;
    ((u32*)gammaT)[((((size_t)b * M_ + m0 + k) * T_) >> 1) + tid] = lo | hi;
  }
}

// ---------------------------------------------------------------------------
// K7: expanded[b,m,c] = sum_t gammaT[m,t]*textT[c,t]  + (-1e30)*suffix[m+1,c]
// ---------------------------------------------------------------------------
__launch_bounds__(256)
__global__ void k7_expanded(const u16* __restrict__ gammaT, const u16* __restrict__ textT,
                            const float* __restrict__ suffix, float* __restrict__ expanded)
{
  __shared__ __align__(16) short As[128][40];
  __shared__ __align__(16) short Bs[128][40];
  const int b   = blockIdx.z;
  const int m0  = blockIdx.x * 128;
  const int c0  = blockIdx.y * 128;
  const int tid = threadIdx.x;
  const int lane = tid & 63, wid = tid >> 6;
  const int wr = wid >> 1, wc = wid & 1;
  const u16* Ab = gammaT + (size_t)b * M_ * T_;
  const u16* Bb = textT  + (size_t)b * C_ * T_;
  f32x4 acc[4][4];
#pragma unroll
  for (int i = 0; i < 4; ++i)
#pragma unroll
    for (int j = 0; j < 4; ++j) acc[i][j] = (f32x4){0.f, 0.f, 0.f, 0.f};

  const int ko  = (tid & 3) * 8;
  const int rb2 = tid >> 2;
  for (int kk = 0; kk < T_; kk += 32) {
    __syncthreads();
#pragma unroll
    for (int it = 0; it < 2; ++it) {
      int r = rb2 + it * 64;
      *(uint4*)&As[r][ko] = *(const uint4*)(Ab + (size_t)(m0 + r) * T_ + kk + ko);
      *(uint4*)&Bs[r][ko] = *(const uint4*)(Bb + (size_t)(c0 + r) * T_ + kk + ko);
    }
    __syncthreads();
    const int k0 = (lane >> 4) * 8;
    bf16x8 af[4], bfr[4];
#pragma unroll
    for (int i = 0; i < 4; ++i) {
      af[i]  = *(const bf16x8*)&As[wr * 64 + i * 16 + (lane & 15)][k0];
      bfr[i] = *(const bf16x8*)&Bs[wc * 64 + i * 16 + (lane & 15)][k0];
    }
#pragma unroll
    for (int i = 0; i < 4; ++i)
#pragma unroll
      for (int j = 0; j < 4; ++j)
        acc[i][j] = __builtin_amdgcn_mfma_f32_16x16x32_bf16(af[i], bfr[j], acc[i][j], 0, 0, 0);
  }
#pragma unroll
  for (int i = 0; i < 4; ++i) {
#pragma unroll
    for (int j = 0; j < 4; ++j) {
#pragma unroll
      for (int rr = 0; rr < 4; ++rr) {
        int m = m0 + wr * 64 + i * 16 + (lane >> 4) * 4 + rr;
        int c = c0 + wc * 64 + j * 16 + (lane & 15);
        int sidx = (m + 1 < T_) ? (m + 1) : T_;
        float sfx = suffix[((size_t)b * (T_ + 1) + sidx) * C_ + c];
        expanded[((size_t)b * M_ + m) * C_ + c] = acc[i][j][rr] + NEGV * sfx;
      }
    }
  }
}

// ---------------------------------------------------------------------------
extern "C" void kernel_launch(void* const* d_in, const int* in_sizes, int n_in,
                              void* d_out, int out_size, void* d_ws, size_t ws_size,
                              hipStream_t stream) {
  const float* text  = (const float*)d_in[0];
  const float* mel   = (const float*)d_in[1];
  const float* noise = (const float*)d_in[2];
  const float* ratio = (const float*)d_in[3];

  const size_t BTM = (size_t)B_ * T_ * M_;   // 16777216
  float* out       = (float*)d_out;
  float* gamma_log = out;
  float* expanded  = out + BTM;

  char* w = (char*)d_ws;
  u16*   ttbuf  = (u16*)  (w + 0);           // [B][T][M] bf16   33554432 B
  float* suffix = (float*)(w + 33554432);    // [B][T+1][C]      16809984 B
  u16*   textT  = (u16*)  (w + 50364416);    // [B][C][T]         8388608 B
  u16*   gammaT = (u16*)  (w + 58753024);    // [B][M][T]        33554432 B
  u16*   Abuf   = (u16*)  (w + 92307456);    // [B][T][M] bf16   33554432 B
  u16*   Bbuf   = (u16*)  (w + 125861888);   // [B][T][M] bf16   33554432 B
  float* CAa    = (float*)(w + 159416320);   // [B][T]              32768 B
  float* CBa    = (float*)(w + 159449088);   // [B][T]              32768 B
  float* partial = (float*)(w + 58753024);   // k3 scratch (gammaT region, pre-k6)

  k3a_partial<<<B_ * 8,          512, 0, stream>>>(text, partial);
  k3b_suffix <<<B_ * 8,          512, 0, stream>>>(text, partial, suffix);
  k3t_textT  <<<dim3(8, 8, 16),  256, 0, stream>>>(text, textT);
  k1_energy  <<<dim3(4, 16, 16), 256, 0, stream>>>(text, mel, noise, ratio, ttbuf);
  k4_dp      <<<32,               64, 0, stream>>>(ttbuf, Abuf, Bbuf, CAa, CBa);
  k6_combine <<<B_ * 64,         256, 0, stream>>>(Abuf, Bbuf, CAa, CBa, gamma_log, gammaT);
  k7_expanded<<<dim3(16, 4, 16), 256, 0, stream>>>(gammaT, textT, suffix, expanded);
}

// Round 6
// 457.549 us; speedup vs baseline: 1.7886x; 1.2603x over previous
//
#include <hip/hip_runtime.h>

#define B_  16
#define T_  512
#define M_  2048
#define C_  512
#define NEGV (-1e30f)
#define L2E 1.4426950408889634f
#define LN2 0.69314718055994531f

typedef unsigned short u16;
typedef unsigned int   u32;
using bf16x8 = __attribute__((ext_vector_type(8))) short;
using f32x4  = __attribute__((ext_vector_type(4))) float;

__device__ __forceinline__ u16 f2bf(float x) {
  u32 u = __float_as_uint(x);
  return (u16)((u + 0x7FFFu + ((u >> 16) & 1u)) >> 16);
}
__device__ __forceinline__ float bf2f(u16 u) {
  return __uint_as_float(((u32)u) << 16);
}
__device__ __forceinline__ float rdlane63(float x) {
  return __int_as_float(__builtin_amdgcn_readlane(__float_as_int(x), 63));
}

// 64-lane inclusive add-scan via DPP (row_shr 1/2/4/8, bcast15, bcast31)
__device__ __forceinline__ float wscan_add(float x) {
  x += __int_as_float(__builtin_amdgcn_update_dpp(0, __float_as_int(x), 0x111, 0xF, 0xF, true));
  x += __int_as_float(__builtin_amdgcn_update_dpp(0, __float_as_int(x), 0x112, 0xF, 0xF, true));
  x += __int_as_float(__builtin_amdgcn_update_dpp(0, __float_as_int(x), 0x114, 0xF, 0xF, true));
  x += __int_as_float(__builtin_amdgcn_update_dpp(0, __float_as_int(x), 0x118, 0xF, 0xF, true));
  x += __int_as_float(__builtin_amdgcn_update_dpp(0, __float_as_int(x), 0x142, 0xA, 0xF, true));
  x += __int_as_float(__builtin_amdgcn_update_dpp(0, __float_as_int(x), 0x143, 0xC, 0xF, true));
  return x;
}
// lane i <- lane i-1 (wave_shr:1), lane0 <- 0
__device__ __forceinline__ float dpp_shr1(float x) {
  return __int_as_float(__builtin_amdgcn_update_dpp(0, __float_as_int(x), 0x138, 0xF, 0xF, true));
}

// ---------------------------------------------------------------------------
// K1: energy GEMM (bf16 MFMA) + gumbel + /temperature -> tt = exp(le - D) bf16
// ---------------------------------------------------------------------------
__launch_bounds__(256)
__global__ void k1_energy(const float* __restrict__ text, const float* __restrict__ mel,
                          const float* __restrict__ noise, const float* __restrict__ ratio,
                          u16* __restrict__ ttbuf)
{
  __shared__ __align__(16) short As[128][40];
  __shared__ __align__(16) short Bs[128][40];
  const int b   = blockIdx.z;
  const int t0  = blockIdx.x * 128;
  const int m0  = blockIdx.y * 128;
  const int tid = threadIdx.x;
  const int lane = tid & 63, wid = tid >> 6;
  const int wr = wid >> 1, wc = wid & 1;
  const float* Ab = text + (size_t)b * T_ * C_;
  const float* Bb = mel  + (size_t)b * M_ * C_;
  f32x4 acc[4][4];
#pragma unroll
  for (int i = 0; i < 4; ++i)
#pragma unroll
    for (int j = 0; j < 4; ++j) acc[i][j] = (f32x4){0.f, 0.f, 0.f, 0.f};

  const int kq = (tid & 7) * 4;
  const int rb = tid >> 3;
  for (int kk = 0; kk < C_; kk += 32) {
    __syncthreads();
#pragma unroll
    for (int it = 0; it < 4; ++it) {
      int r = rb + it * 32;
      float4 va = *(const float4*)(Ab + (size_t)(t0 + r) * C_ + kk + kq);
      As[r][kq + 0] = (short)f2bf(va.x); As[r][kq + 1] = (short)f2bf(va.y);
      As[r][kq + 2] = (short)f2bf(va.z); As[r][kq + 3] = (short)f2bf(va.w);
      float4 vb = *(const float4*)(Bb + (size_t)(m0 + r) * C_ + kk + kq);
      Bs[r][kq + 0] = (short)f2bf(vb.x); Bs[r][kq + 1] = (short)f2bf(vb.y);
      Bs[r][kq + 2] = (short)f2bf(vb.z); Bs[r][kq + 3] = (short)f2bf(vb.w);
    }
    __syncthreads();
    const int k0 = (lane >> 4) * 8;
    bf16x8 af[4], bfr[4];
#pragma unroll
    for (int i = 0; i < 4; ++i) {
      af[i]  = *(const bf16x8*)&As[wr * 64 + i * 16 + (lane & 15)][k0];
      bfr[i] = *(const bf16x8*)&Bs[wc * 64 + i * 16 + (lane & 15)][k0];
    }
#pragma unroll
    for (int i = 0; i < 4; ++i)
#pragma unroll
      for (int j = 0; j < 4; ++j)
        acc[i][j] = __builtin_amdgcn_mfma_f32_16x16x32_bf16(af[i], bfr[j], acc[i][j], 0, 0, 0);
  }
  const float invT = 1.0f / (0.1f + 0.9f * ratio[0]);
  const float D2 = 14.5f * invT * L2E;
#pragma unroll
  for (int i = 0; i < 4; ++i) {
#pragma unroll
    for (int j = 0; j < 4; ++j) {
#pragma unroll
      for (int rr = 0; rr < 4; ++rr) {
        int t = t0 + wr * 64 + i * 16 + (lane >> 4) * 4 + rr;
        int m = m0 + wc * 64 + j * 16 + (lane & 15);
        size_t idx = ((size_t)b * T_ + t) * M_ + m;
        float en = acc[i][j][rr] * (1.0f / 512.0f);
        float u  = noise[idx];
        float nl = -LN2 * __builtin_amdgcn_logf(u);    // -ln u  (>0)
        float g  = -LN2 * __builtin_amdgcn_logf(nl);   // -ln(-ln u)
        float le = (en + g) * invT;
        float tv = __builtin_amdgcn_exp2f(__builtin_fmaf(le, L2E, -D2));
        ttbuf[idx] = f2bf(tv);
      }
    }
  }
}

// ---------------------------------------------------------------------------
// K2r: R[t][j] = bf16( 1 / sum_{k>=j} tt[t][k] )  (parallel per row)
// ---------------------------------------------------------------------------
__launch_bounds__(256)
__global__ void k2r(const u16* __restrict__ ttbuf, u16* __restrict__ Rbuf)
{
  const size_t row = blockIdx.x;          // b*T + t
  const u16* src = ttbuf + row * M_;
  u16* dst = Rbuf + row * M_;
  const int tid = threadIdx.x, lane = tid & 63, wid = tid >> 6;
  const int c0 = tid * 8;
  uint4 w = *(const uint4*)(src + c0);
  float x[8];
  x[0] = __uint_as_float(w.x << 16); x[1] = __uint_as_float(w.x & 0xFFFF0000u);
  x[2] = __uint_as_float(w.y << 16); x[3] = __uint_as_float(w.y & 0xFFFF0000u);
  x[4] = __uint_as_float(w.z << 16); x[5] = __uint_as_float(w.z & 0xFFFF0000u);
  x[6] = __uint_as_float(w.w << 16); x[7] = __uint_as_float(w.w & 0xFFFF0000u);
#pragma unroll
  for (int i = 6; i >= 0; --i) x[i] += x[i + 1];     // local suffix incl
  float v = x[0];
#pragma unroll
  for (int d = 1; d < 64; d <<= 1) {
    float t = __shfl_down(v, d);
    if (lane < 64 - d) v += t;
  }
  float e = __shfl_down(v, 1);
  if (lane == 63) e = 0.f;                // suffix over lanes strictly after
  __shared__ float part[4];
  if (lane == 0) part[wid] = v;
  __syncthreads();
  float we = 0.f;
  for (int w2 = wid + 1; w2 < 4; ++w2) we += part[w2];
  float off = e + we;                     // sum over cols >= c0+8
  u32 o[4];
#pragma unroll
  for (int i = 0; i < 4; ++i) {
    float r0 = __builtin_amdgcn_rcpf(x[2*i]     + off);
    float r1 = __builtin_amdgcn_rcpf(x[2*i + 1] + off);
    o[i] = __builtin_amdgcn_perm(__float_as_uint(r1), __float_as_uint(r0), 0x07060302u);
  }
  *(uint4*)(dst + c0) = make_uint4(o[0], o[1], o[2], o[3]);
}

// ---------------------------------------------------------------------------
// K3a: per-chunk partial sums of text over t (chunk = 64 rows)
// ---------------------------------------------------------------------------
__launch_bounds__(512)
__global__ void k3a_partial(const float* __restrict__ text, float* __restrict__ partial)
{
  const int b = blockIdx.x >> 3, ch = blockIdx.x & 7, c = threadIdx.x;
  const float* tb = text + (size_t)b * T_ * C_ + (size_t)ch * 64 * C_ + c;
  float s = 0.f;
#pragma unroll 8
  for (int tt = 0; tt < 64; ++tt) s += tb[(size_t)tt * C_];
  partial[((size_t)b * 8 + ch) * C_ + c] = s;
}

// ---------------------------------------------------------------------------
// K3b: suffix[b,t,c] = sum_{t'>=t} text[b,t',c]; layout [B][T+1][C], row T = 0
// ---------------------------------------------------------------------------
__launch_bounds__(512)
__global__ void k3b_suffix(const float* __restrict__ text, const float* __restrict__ partial,
                           float* __restrict__ suffix)
{
  const int b = blockIdx.x >> 3, ch = blockIdx.x & 7, c = threadIdx.x;
  float off = 0.f;
  for (int ch2 = ch + 1; ch2 < 8; ++ch2) off += partial[((size_t)b * 8 + ch2) * C_ + c];
  const float* tb = text + (size_t)b * T_ * C_ + (size_t)ch * 64 * C_ + c;
  float* sb = suffix + (size_t)b * (T_ + 1) * C_ + (size_t)ch * 64 * C_ + c;
  if (ch == 7) sb[(size_t)64 * C_] = 0.f;   // row T_
  float s = off;
  for (int tt = 63; tt >= 0; --tt) {
    s += tb[(size_t)tt * C_];
    sb[(size_t)tt * C_] = s;
  }
}

// ---------------------------------------------------------------------------
// K3t: textT[b,c,t] = bf16(text[b,t,c])  (LDS transpose tiles)
// ---------------------------------------------------------------------------
__launch_bounds__(256)
__global__ void k3t_textT(const float* __restrict__ text, u16* __restrict__ textT)
{
  __shared__ u16 tile[64][66];
  const int b  = blockIdx.z;
  const int t0 = blockIdx.x * 64;
  const int c0 = blockIdx.y * 64;
  const int tid = threadIdx.x;
  const int j = tid & 63, i4 = tid >> 6;
#pragma unroll
  for (int it = 0; it < 16; ++it) {
    int i = it * 4 + i4;
    tile[i][j] = f2bf(text[((size_t)b * T_ + t0 + i) * C_ + c0 + j]);
  }
  __syncthreads();
#pragma unroll
  for (int it = 0; it < 16; ++it) {
    int cc = it * 4 + i4;
    textT[((size_t)b * C_ + c0 + cc) * T_ + t0 + j] = tile[j][cc];
  }
}

// ---------------------------------------------------------------------------
// K4: alpha (blocks 0..15) / beta (blocks 16..31). ONE WAVE per chain.
//     Linear-domain DP with precomputed R = 1/S (bf16, k2r). Per step:
//     fold cum = A_shift*R during unpack -> ONE prefix scan -> ONE wave scan
//     -> A = tt*fma(cum,zr,fz). 2 trans/step. DPP wave_shr for the shift.
//     Depth-2 double-buffered raw prefetch (tt+R).
// ---------------------------------------------------------------------------
__launch_bounds__(64, 1)
__global__ void k4_dp(const u16* __restrict__ ttbuf, const u16* __restrict__ Rbuf,
                      u16* __restrict__ Abuf, u16* __restrict__ Bbuf,
                      float* __restrict__ CAa, float* __restrict__ CBa)
{
  const int blk = blockIdx.x;
  const int b   = blk & 15;
  const int lane = threadIdx.x & 63;
  const u16* TT = ttbuf + (size_t)b * T_ * M_;
  const u16* RR = Rbuf  + (size_t)b * T_ * M_;
  uint4 rawT[2][4], rawR[2][4];
  float arr[32], cum[32], A[32];
  float Cv = 0.f;

  if (blk < 16) {
    // ======================= alpha =======================
    const int c0 = lane * 32;
    u16* AO = Abuf + (size_t)b * T_ * M_;
    float* CO = CAa + (size_t)b * T_;

#define TLDA(BUF, R) { \
    const uint4* pt_ = (const uint4*)(TT + (size_t)(R) * M_ + c0); \
    const uint4* pr_ = (const uint4*)(RR + (size_t)(R) * M_ + c0); \
    rawT[BUF][0]=pt_[0]; rawT[BUF][1]=pt_[1]; rawT[BUF][2]=pt_[2]; rawT[BUF][3]=pt_[3]; \
    rawR[BUF][0]=pr_[0]; rawR[BUF][1]=pr_[1]; rawR[BUF][2]=pr_[2]; rawR[BUF][3]=pr_[3]; }

#define FOLD2A(E, W) { \
    cum[E]   = A[(E)-1] * __uint_as_float((W) << 16); \
    cum[(E)+1] = A[E]   * __uint_as_float((W) & 0xFFFF0000u); }

#define ASTEP(BUF, RIDX, FIRST) { \
    const int r_ = (RIDX); \
    /* unpack tt -> arr */ \
    _Pragma("unroll") for (int q = 0; q < 4; ++q) { \
      u32 w0 = rawT[BUF][q].x, w1 = rawT[BUF][q].y, w2 = rawT[BUF][q].z, w3 = rawT[BUF][q].w; \
      arr[8*q+0] = __uint_as_float(w0 << 16); arr[8*q+1] = __uint_as_float(w0 & 0xFFFF0000u); \
      arr[8*q+2] = __uint_as_float(w1 << 16); arr[8*q+3] = __uint_as_float(w1 & 0xFFFF0000u); \
      arr[8*q+4] = __uint_as_float(w2 << 16); arr[8*q+5] = __uint_as_float(w2 & 0xFFFF0000u); \
      arr[8*q+6] = __uint_as_float(w3 << 16); arr[8*q+7] = __uint_as_float(w3 & 0xFFFF0000u); } \
    /* fold cum[e] = A[e-1]*R[e]; elem0 uses DPP wave_shr of A[31] */ \
    { float am1 = dpp_shr1(A[31]); \
      if (FIRST) am1 = (lane == 0) ? 1.f : am1; \
      u32 v0 = rawR[BUF][0].x; \
      cum[0] = am1 * __uint_as_float(v0 << 16); \
      cum[1] = A[0] * __uint_as_float(v0 & 0xFFFF0000u); } \
    FOLD2A(2, rawR[BUF][0].y) FOLD2A(4, rawR[BUF][0].z) FOLD2A(6, rawR[BUF][0].w) \
    _Pragma("unroll") for (int q = 1; q < 4; ++q) { \
      FOLD2A(8*q+0, rawR[BUF][q].x) FOLD2A(8*q+2, rawR[BUF][q].y) \
      FOLD2A(8*q+4, rawR[BUF][q].z) FOLD2A(8*q+6, rawR[BUF][q].w) } \
    /* prefetch row r+2 into this buffer */ \
    TLDA(BUF, (r_ + 2 < T_) ? r_ + 2 : T_ - 1) \
    __builtin_amdgcn_sched_barrier(0); \
    /* prefix cumsum */ \
    _Pragma("unroll") for (int c = 0; c < 4; ++c) \
      _Pragma("unroll") for (int k = 1; k < 8; ++k) cum[8*c+k] += cum[8*c+k-1]; \
    { float Te = (cum[7] + cum[15]) + (cum[23] + cum[31]); \
      float v_ = wscan_add(Te); \
      float exw = v_ - Te; \
      float Zt = rdlane63(v_); \
      float f0 = exw, f1 = f0+cum[7], f2 = f1+cum[15], f3 = f2+cum[23]; \
      float Zc = fmaxf(Zt, 1e-35f); \
      float zr = __builtin_amdgcn_rcpf(Zc); \
      Cv += LN2 * __builtin_amdgcn_logf(Zc); \
      if (lane == 0) CO[r_] = Cv; \
      float fz0 = f0*zr, fz1 = f1*zr, fz2 = f2*zr, fz3 = f3*zr; \
      _Pragma("unroll") for (int k = 0; k < 8; ++k) { \
        A[k]    = arr[k]    * __builtin_fmaf(cum[k],    zr, fz0); \
        A[8+k]  = arr[8+k]  * __builtin_fmaf(cum[8+k],  zr, fz1); \
        A[16+k] = arr[16+k] * __builtin_fmaf(cum[16+k], zr, fz2); \
        A[24+k] = arr[24+k] * __builtin_fmaf(cum[24+k], zr, fz3); } } \
    { u32 w_[16]; \
      _Pragma("unroll") for (int d = 0; d < 16; ++d) \
        w_[d] = __builtin_amdgcn_perm(__float_as_uint(A[2*d+1]), __float_as_uint(A[2*d]), 0x07060302u); \
      uint4* op = (uint4*)(AO + (size_t)r_ * M_ + c0); \
      op[0] = make_uint4(w_[0],w_[1],w_[2],w_[3]); \
      op[1] = make_uint4(w_[4],w_[5],w_[6],w_[7]); \
      op[2] = make_uint4(w_[8],w_[9],w_[10],w_[11]); \
      op[3] = make_uint4(w_[12],w_[13],w_[14],w_[15]); } \
  }

#pragma unroll
    for (int e = 0; e < 32; ++e) A[e] = 0.f;
    TLDA(0, 0) TLDA(1, 1)
    ASTEP(0, 0, true)
    ASTEP(1, 1, false)
    for (int r = 2; r < T_; r += 2) {
      ASTEP(0, r, false)
      ASTEP(1, r + 1, false)
    }
  } else {
    // ======================= beta (reversed frame) =======================
    const int jb = M_ - 32 - lane * 32;   // element e <-> column j = jb + 31 - e
    u16* BO = Bbuf + (size_t)b * T_ * M_;
    float* CO = CBa + (size_t)b * T_;

#define TLDB(BUF, R) { \
    const uint4* pt_ = (const uint4*)(TT + (size_t)(R) * M_ + jb); \
    const uint4* pr_ = (const uint4*)(RR + (size_t)(R) * M_ + jb); \
    rawT[BUF][0]=pt_[0]; rawT[BUF][1]=pt_[1]; rawT[BUF][2]=pt_[2]; rawT[BUF][3]=pt_[3]; \
    rawR[BUF][0]=pr_[0]; rawR[BUF][1]=pr_[1]; rawR[BUF][2]=pr_[2]; rawR[BUF][3]=pr_[3]; }

#define FOLD2B(E, W) { \
    cum[E]     = A[E]     * __uint_as_float((W) << 16); \
    cum[(E)-1] = A[(E)-1] * __uint_as_float((W) & 0xFFFF0000u); }

#define BSTEP(BUF, TIDX) { \
    const int t_ = (TIDX); \
    /* unpack R -> arr (reversed) */ \
    _Pragma("unroll") for (int q = 0; q < 4; ++q) { \
      u32 w0 = rawR[BUF][q].x, w1 = rawR[BUF][q].y, w2 = rawR[BUF][q].z, w3 = rawR[BUF][q].w; \
      arr[31-8*q] = __uint_as_float(w0 << 16); arr[30-8*q] = __uint_as_float(w0 & 0xFFFF0000u); \
      arr[29-8*q] = __uint_as_float(w1 << 16); arr[28-8*q] = __uint_as_float(w1 & 0xFFFF0000u); \
      arr[27-8*q] = __uint_as_float(w2 << 16); arr[26-8*q] = __uint_as_float(w2 & 0xFFFF0000u); \
      arr[25-8*q] = __uint_as_float(w3 << 16); arr[24-8*q] = __uint_as_float(w3 & 0xFFFF0000u); } \
    /* fold cum[e] = B[e]*tt[e] (reversed) */ \
    _Pragma("unroll") for (int q = 0; q < 4; ++q) { \
      FOLD2B(31-8*q, rawT[BUF][q].x) FOLD2B(29-8*q, rawT[BUF][q].y) \
      FOLD2B(27-8*q, rawT[BUF][q].z) FOLD2B(25-8*q, rawT[BUF][q].w) } \
    { int tp_ = t_ - 2; if (tp_ < 0) tp_ = 0; TLDB(BUF, tp_) } \
    __builtin_amdgcn_sched_barrier(0); \
    /* prefix cumsum */ \
    _Pragma("unroll") for (int c = 0; c < 4; ++c) \
      _Pragma("unroll") for (int k = 1; k < 8; ++k) cum[8*c+k] += cum[8*c+k-1]; \
    { float Te = (cum[7] + cum[15]) + (cum[23] + cum[31]); \
      float v_ = wscan_add(Te); \
      float exw = v_ - Te; \
      float Zb = rdlane63(v_); \
      float f0 = exw, f1 = f0+cum[7], f2 = f1+cum[15], f3 = f2+cum[23]; \
      float Zc = fmaxf(Zb, 1e-35f); \
      float zr = __builtin_amdgcn_rcpf(Zc); \
      Cv += LN2 * __builtin_amdgcn_logf(Zc); \
      float fz0 = f0*zr, fz1 = f1*zr, fz2 = f2*zr, fz3 = f3*zr; \
      _Pragma("unroll") for (int k = 0; k < 8; ++k) { \
        A[k]    = arr[k]    * __builtin_fmaf(cum[k],    zr, fz0); \
        A[8+k]  = arr[8+k]  * __builtin_fmaf(cum[8+k],  zr, fz1); \
        A[16+k] = arr[16+k] * __builtin_fmaf(cum[16+k], zr, fz2); \
        A[24+k] = arr[24+k] * __builtin_fmaf(cum[24+k], zr, fz3); } } \
    if (t_ >= 0) { \
      if (lane == 0) CO[t_] = Cv; \
      u32 w_[16]; \
      _Pragma("unroll") for (int d = 0; d < 16; ++d) \
        w_[d] = __builtin_amdgcn_perm(__float_as_uint(A[30-2*d]), __float_as_uint(A[31-2*d]), 0x07060302u); \
      uint4* op = (uint4*)(BO + (size_t)t_ * M_ + jb); \
      op[0] = make_uint4(w_[0],w_[1],w_[2],w_[3]); \
      op[1] = make_uint4(w_[4],w_[5],w_[6],w_[7]); \
      op[2] = make_uint4(w_[8],w_[9],w_[10],w_[11]); \
      op[3] = make_uint4(w_[12],w_[13],w_[14],w_[15]); } \
  }

    // init row T-1: beta=0 -> B=1 everywhere; +1.0 at j=M-1 -> B=e (faithful)
#pragma unroll
    for (int e = 0; e < 32; ++e) A[e] = 1.f;
    if (lane == 0) A[0] = 2.718281828f;
    { u32 w_[16];
#pragma unroll
      for (int d = 0; d < 16; ++d)
        w_[d] = __builtin_amdgcn_perm(__float_as_uint(A[30-2*d]), __float_as_uint(A[31-2*d]), 0x07060302u);
      uint4* op = (uint4*)(BO + (size_t)(T_ - 1) * M_ + jb);
      op[0] = make_uint4(w_[0],w_[1],w_[2],w_[3]);
      op[1] = make_uint4(w_[4],w_[5],w_[6],w_[7]);
      op[2] = make_uint4(w_[8],w_[9],w_[10],w_[11]);
      op[3] = make_uint4(w_[12],w_[13],w_[14],w_[15]);
      if (lane == 0) CO[T_ - 1] = 0.f;
    }
    TLDB(0, T_ - 2) TLDB(1, T_ - 3)
    BSTEP(0, T_ - 2)
    BSTEP(1, T_ - 3)
    for (int t = T_ - 4; t >= 0; t -= 2) {
      BSTEP(0, t)
      BSTEP(1, t - 1)
    }
  }
}

// ---------------------------------------------------------------------------
// K6: gamma = (t<=m) ? LN2*(log2 A + log2 B) + CA[t]+CB[t] : NEGV  (clamped);
//     LSE over t; gamma_log -> d_out; gammaT bf16 (masked) via LDS stash.
// ---------------------------------------------------------------------------
__launch_bounds__(256)
__global__ void k6_combine(const u16* __restrict__ Abuf, const u16* __restrict__ Bbuf,
                           const float* __restrict__ CAa, const float* __restrict__ CBa,
                           float* __restrict__ gamma_log, u16* __restrict__ gammaT)
{
  __shared__ u16 gst[32][514];
  __shared__ float cd[T_];
  __shared__ float smx[8][32], ssm[8][32];
  const int b  = blockIdx.x >> 6;
  const int m0 = (blockIdx.x & 63) * 32;
  const int tid = threadIdx.x;
  const int mi = tid & 31, ti = tid >> 5;
  const int m = m0 + mi;
  const size_t base = (size_t)b * T_ * M_ + m;

  cd[tid]       = CAa[b * T_ + tid]       + CBa[b * T_ + tid];
  cd[tid + 256] = CAa[b * T_ + tid + 256] + CBa[b * T_ + tid + 256];
  __syncthreads();

  float mx = -3.0e38f, s = 0.f;
  for (int t = ti; t < T_; t += 8) {
    float a  = bf2f(Abuf[base + (size_t)t * M_]);
    float bb = bf2f(Bbuf[base + (size_t)t * M_]);
    float g;
    if (t <= m) {
      g = __builtin_fmaf(__builtin_amdgcn_logf(a) + __builtin_amdgcn_logf(bb), LN2, cd[t]);
      g = fmaxf(g, -1e8f);            // underflow clamp (error << thresholds)
    } else g = NEGV;
    gst[mi][t] = f2bf(g);
    if (g > mx) { s = s * __builtin_amdgcn_exp2f((mx - g) * L2E) + 1.f; mx = g; }
    else        { s += __builtin_amdgcn_exp2f((g - mx) * L2E); }
  }
  smx[ti][mi] = mx; ssm[ti][mi] = s;
  __syncthreads();
  float Mv = smx[0][mi], Sv = ssm[0][mi];
#pragma unroll
  for (int k = 1; k < 8; ++k) {
    float Mk = smx[k][mi], Sk = ssm[k][mi];
    if (Mk > Mv) { Sv = Sv * __builtin_amdgcn_exp2f((Mv - Mk) * L2E) + Sk; Mv = Mk; }
    else         { Sv += Sk * __builtin_amdgcn_exp2f((Mk - Mv) * L2E); }
  }
  const float lse = Mv + LN2 * __builtin_amdgcn_logf(Sv);

  // pass2a: gamma_log (masked entries exact NEGV, not bf16-rounded)
  for (int t = ti; t < T_; t += 8) {
    float g = (t <= m) ? bf2f(gst[mi][t]) : NEGV;
    gamma_log[base + (size_t)t * M_] = g - lse;
  }
  // pass2b: gammaT[b, m0+k, t] from LDS stash (coalesced u32 rows)
  for (int k = 0; k < 32; ++k) {
    u32 val = *(const u32*)&gst[k][2 * tid];
    int mr = m0 + k;
    u32 lo = (2 * tid     <= mr) ? (val & 0x0000FFFFu) : 0u;
    u32 hi = (2 * tid + 1 <= mr) ? (val & 0xFFFF0000u) : 0u;
    ((u32*)gammaT)[((((size_t)b * M_ + m0 + k) * T_) >> 1) + tid] = lo | hi;
  }
}

// ---------------------------------------------------------------------------
// K7: expanded[b,m,c] = sum_t gammaT[m,t]*textT[c,t]  + (-1e30)*suffix[m+1,c]
// ---------------------------------------------------------------------------
__launch_bounds__(256)
__global__ void k7_expanded(const u16* __restrict__ gammaT, const u16* __restrict__ textT,
                            const float* __restrict__ suffix, float* __restrict__ expanded)
{
  __shared__ __align__(16) short As[128][40];
  __shared__ __align__(16) short Bs[128][40];
  const int b   = blockIdx.z;
  const int m0  = blockIdx.x * 128;
  const int c0  = blockIdx.y * 128;
  const int tid = threadIdx.x;
  const int lane = tid & 63, wid = tid >> 6;
  const int wr = wid >> 1, wc = wid & 1;
  const u16* Ab = gammaT + (size_t)b * M_ * T_;
  const u16* Bb = textT  + (size_t)b * C_ * T_;
  f32x4 acc[4][4];
#pragma unroll
  for (int i = 0; i < 4; ++i)
#pragma unroll
    for (int j = 0; j < 4; ++j) acc[i][j] = (f32x4){0.f, 0.f, 0.f, 0.f};

  const int ko  = (tid & 3) * 8;
  const int rb2 = tid >> 2;
  for (int kk = 0; kk < T_; kk += 32) {
    __syncthreads();
#pragma unroll
    for (int it = 0; it < 2; ++it) {
      int r = rb2 + it * 64;
      *(uint4*)&As[r][ko] = *(const uint4*)(Ab + (size_t)(m0 + r) * T_ + kk + ko);
      *(uint4*)&Bs[r][ko] = *(const uint4*)(Bb + (size_t)(c0 + r) * T_ + kk + ko);
    }
    __syncthreads();
    const int k0 = (lane >> 4) * 8;
    bf16x8 af[4], bfr[4];
#pragma unroll
    for (int i = 0; i < 4; ++i) {
      af[i]  = *(const bf16x8*)&As[wr * 64 + i * 16 + (lane & 15)][k0];
      bfr[i] = *(const bf16x8*)&Bs[wc * 64 + i * 16 + (lane & 15)][k0];
    }
#pragma unroll
    for (int i = 0; i < 4; ++i)
#pragma unroll
      for (int j = 0; j < 4; ++j)
        acc[i][j] = __builtin_amdgcn_mfma_f32_16x16x32_bf16(af[i], bfr[j], acc[i][j], 0, 0, 0);
  }
#pragma unroll
  for (int i = 0; i < 4; ++i) {
#pragma unroll
    for (int j = 0; j < 4; ++j) {
#pragma unroll
      for (int rr = 0; rr < 4; ++rr) {
        int m = m0 + wr * 64 + i * 16 + (lane >> 4) * 4 + rr;
        int c = c0 + wc * 64 + j * 16 + (lane & 15);
        int sidx = (m + 1 < T_) ? (m + 1) : T_;
        float sfx = suffix[((size_t)b * (T_ + 1) + sidx) * C_ + c];
        expanded[((size_t)b * M_ + m) * C_ + c] = acc[i][j][rr] + NEGV * sfx;
      }
    }
  }
}

// ---------------------------------------------------------------------------
extern "C" void kernel_launch(void* const* d_in, const int* in_sizes, int n_in,
                              void* d_out, int out_size, void* d_ws, size_t ws_size,
                              hipStream_t stream) {
  const float* text  = (const float*)d_in[0];
  const float* mel   = (const float*)d_in[1];
  const float* noise = (const float*)d_in[2];
  const float* ratio = (const float*)d_in[3];

  const size_t BTM = (size_t)B_ * T_ * M_;   // 16777216
  float* out       = (float*)d_out;
  float* gamma_log = out;
  float* expanded  = out + BTM;

  char* w = (char*)d_ws;
  u16*   ttbuf  = (u16*)  (w + 0);           // [B][T][M] bf16   33554432 B
  u16*   Rbuf   = (u16*)  (w + 33554432);    // [B][T][M] bf16   33554432 B
  float* suffix = (float*)(w + 67108864);    // [B][T+1][C]      16809984 B
  u16*   textT  = (u16*)  (w + 83918848);    // [B][C][T]         8388608 B
  u16*   gammaT = (u16*)  (w + 92307456);    // [B][M][T]        33554432 B
  u16*   Abuf   = (u16*)  (w + 125861888);   // [B][T][M] bf16   33554432 B
  u16*   Bbuf   = (u16*)  (w + 159416320);   // [B][T][M] bf16 -> ends 192970752 B
  float* partial = (float*)(w + 92307456);   // k3 scratch (gammaT region, pre-k6)
  // CA/CB scalars live in the `expanded` output region (overwritten later by k7)
  float* CAa = expanded;                     // [B][T]  32768 B
  float* CBa = expanded + (size_t)B_ * T_;   // [B][T]  32768 B

  k3a_partial<<<B_ * 8,          512, 0, stream>>>(text, partial);
  k3b_suffix <<<B_ * 8,          512, 0, stream>>>(text, partial, suffix);
  k3t_textT  <<<dim3(8, 8, 16),  256, 0, stream>>>(text, textT);
  k1_energy  <<<dim3(4, 16, 16), 256, 0, stream>>>(text, mel, noise, ratio, ttbuf);
  k2r        <<<B_ * T_,         256, 0, stream>>>(ttbuf, Rbuf);
  k4_dp      <<<32,               64, 0, stream>>>(ttbuf, Rbuf, Abuf, Bbuf, CAa, CBa);
  k6_combine <<<B_ * 64,         256, 0, stream>>>(Abuf, Bbuf, CAa, CBa, gamma_log, gammaT);
  k7_expanded<<<dim3(16, 4, 16), 256, 0, stream>>>(gammaT, textT, suffix, expanded);
}